// Round 8
// baseline (269.381 us; speedup 1.0000x reference)
//
#include <hip/hip_runtime.h>
#include <hip/hip_bf16.h>
#include <stddef.h>
#include <stdint.h>

#define DIM 1024
#define NH 16
#define HD 64
#define BATCH 2
#define SEQ 2048
#define ROWS (BATCH * SEQ) /* 4096 */
#define KVB 128
#define NT (SEQ / KVB) /* 16 */

typedef short bf16x8 __attribute__((ext_vector_type(8)));
typedef float f32x4 __attribute__((ext_vector_type(4)));
typedef unsigned short u16;
typedef unsigned short u16x4v __attribute__((ext_vector_type(4)));

#define AS1 __attribute__((address_space(1)))
#define AS3 __attribute__((address_space(3)))

__device__ __forceinline__ void gload16(const u16* g, u16* l) {
  __builtin_amdgcn_global_load_lds((const AS1 void*)g, (AS3 void*)l, 16, 0, 0);
}

__device__ __forceinline__ u16 f2bf(float f) {
  union { float f; unsigned u; } v; v.f = f;
  unsigned r = v.u + 0x7FFFu + ((v.u >> 16) & 1u);
  return (u16)(r >> 16);
}

// ---- merged: convert x (fp32->bf16) [bid<4096] + weight transpose [bid>=4096]
__global__ __launch_bounds__(256) void prep(
    const float* __restrict__ x, const float* __restrict__ wq,
    const float* __restrict__ wk, const float* __restrict__ wv,
    const float* __restrict__ wo, u16* __restrict__ xb,
    u16* __restrict__ wqkvT, u16* __restrict__ woT) {
  __shared__ float tile[32][33];
  int bid = blockIdx.x;
  int t = threadIdx.x;
  if (bid < 4096) {
    int i = (bid * 256 + t) * 4;
    float4 v = *(const float4*)(x + i);
    u16x4v o;
    o.x = f2bf(v.x); o.y = f2bf(v.y); o.z = f2bf(v.z); o.w = f2bf(v.w);
    *(u16x4v*)(xb + i) = o;
  } else {
    int bb = bid - 4096;
    int mat = bb >> 10;
    int tIdx = bb & 1023;
    int tr = tIdx >> 5, tc = tIdx & 31;
    const float* src = mat == 0 ? wq : mat == 1 ? wk : mat == 2 ? wv : wo;
#pragma unroll
    for (int i = 0; i < 4; ++i) {
      int idx = i * 256 + t;
      int r = idx >> 5, c = idx & 31;
      tile[r][c] = src[(tr * 32 + r) * DIM + tc * 32 + c];
    }
    __syncthreads();
    u16* dst = (mat < 3) ? (wqkvT + mat * DIM * DIM) : woT;
#pragma unroll
    for (int i = 0; i < 4; ++i) {
      int idx = i * 256 + t;
      int r = idx >> 5, c = idx & 31;
      dst[(tc * 32 + r) * DIM + tr * 32 + c] = f2bf(tile[c][r]);
    }
  }
}

// ------- bf16 GEMM, B^T input (m97 structure: 128x128 tile, BK=32,
//         global_load_lds width-16, linear LDS) -------
__global__ __launch_bounds__(256) void gemm_bt(
    const u16* __restrict__ A, const u16* __restrict__ BT,
    float* __restrict__ C, int M, int N, int K) {
  __shared__ u16 As[128 * 32];
  __shared__ u16 Bs[128 * 32];
  int ntn = N >> 7;
  int tm = blockIdx.x / ntn, tn = blockIdx.x % ntn;
  int m0 = tm << 7, n0 = tn << 7;
  int t = threadIdx.x;
  int w = t >> 6, lane = t & 63;
  int l15 = lane & 15, l4 = lane >> 4;
  int wr = w >> 1, wc = w & 1;

  f32x4 acc[4][4];
#pragma unroll
  for (int i = 0; i < 4; ++i)
#pragma unroll
    for (int j = 0; j < 4; ++j) acc[i][j] = (f32x4){0.f, 0.f, 0.f, 0.f};

  int srow = t >> 2, scol = (t & 3) << 3;
  const u16* Ag = A + (size_t)(m0 + srow) * K + scol;
  const u16* Bg = BT + (size_t)(n0 + srow) * K + scol;
  u16* Asl = &As[t * 8];
  u16* Bsl = &Bs[t * 8];
  size_t half = (size_t)64 * K;

  for (int kt = 0; kt < K; kt += 32) {
    __syncthreads();
    gload16(Ag + kt, Asl);
    gload16(Ag + half + kt, Asl + 2048);
    gload16(Bg + kt, Bsl);
    gload16(Bg + half + kt, Bsl + 2048);
    __syncthreads();
    bf16x8 af[4], bfr[4];
#pragma unroll
    for (int i = 0; i < 4; ++i)
      af[i] = *(const bf16x8*)(&As[(wr * 64 + i * 16 + l15) * 32 + l4 * 8]);
#pragma unroll
    for (int j = 0; j < 4; ++j)
      bfr[j] = *(const bf16x8*)(&Bs[(wc * 64 + j * 16 + l15) * 32 + l4 * 8]);
#pragma unroll
    for (int i = 0; i < 4; ++i)
#pragma unroll
      for (int j = 0; j < 4; ++j)
        acc[i][j] = __builtin_amdgcn_mfma_f32_16x16x32_bf16(af[i], bfr[j],
                                                            acc[i][j], 0, 0, 0);
  }
#pragma unroll
  for (int i = 0; i < 4; ++i)
#pragma unroll
    for (int j = 0; j < 4; ++j) {
      int m = m0 + wr * 64 + i * 16 + l4 * 4;
      int n = n0 + wc * 64 + j * 16 + l15;
#pragma unroll
      for (int r = 0; r < 4; ++r) C[(size_t)(m + r) * N + n] = acc[i][j][r];
    }
}

// ---- LN + rotary for Q,K rows; emits bf16 Q,K in [b][h][s][d] ----
__global__ __launch_bounds__(256) void post_qk(
    const float* __restrict__ qkv, const float* __restrict__ fsin,
    const float* __restrict__ fcos, const float* __restrict__ qsc,
    const float* __restrict__ qbi, const float* __restrict__ ksc,
    const float* __restrict__ kbi, u16* __restrict__ Q, u16* __restrict__ Kk) {
  int row = blockIdx.x;  // b*SEQ + s
  int b = row >> 11, s = row & 2047;
  int t = threadIdx.x;
  const float* qrow = qkv + (size_t)row * 3072;
  const float* krow = qrow + DIM;
  float4 qv = *(const float4*)(qrow + t * 4);
  float4 kv = *(const float4*)(krow + t * 4);
  float qsum = qv.x + qv.y + qv.z + qv.w;
  float qss = qv.x * qv.x + qv.y * qv.y + qv.z * qv.z + qv.w * qv.w;
  float ksum = kv.x + kv.y + kv.z + kv.w;
  float kss = kv.x * kv.x + kv.y * kv.y + kv.z * kv.z + kv.w * kv.w;
#pragma unroll
  for (int off = 1; off < 64; off <<= 1) {
    qsum += __shfl_xor(qsum, off, 64);
    qss += __shfl_xor(qss, off, 64);
    ksum += __shfl_xor(ksum, off, 64);
    kss += __shfl_xor(kss, off, 64);
  }
  __shared__ float red[4][4];
  int w = t >> 6;
  if ((t & 63) == 0) {
    red[w][0] = qsum; red[w][1] = qss; red[w][2] = ksum; red[w][3] = kss;
  }
  __syncthreads();
  qsum = red[0][0] + red[1][0] + red[2][0] + red[3][0];
  qss = red[0][1] + red[1][1] + red[2][1] + red[3][1];
  ksum = red[0][2] + red[1][2] + red[2][2] + red[3][2];
  kss = red[0][3] + red[1][3] + red[2][3] + red[3][3];
  const float inv = 1.0f / 1024.0f;
  float muq = qsum * inv;
  float rq = rsqrtf(qss * inv - muq * muq + 1e-6f);
  float muk = ksum * inv;
  float rk = rsqrtf(kss * inv - muk * muk + 1e-6f);

  int e0 = t * 4;
  int h = e0 >> 6, d0 = e0 & 63;
  float q0 = (qv.x - muq) * rq * qsc[e0 + 0] + qbi[e0 + 0];
  float q1 = (qv.y - muq) * rq * qsc[e0 + 1] + qbi[e0 + 1];
  float q2 = (qv.z - muq) * rq * qsc[e0 + 2] + qbi[e0 + 2];
  float q3 = (qv.w - muq) * rq * qsc[e0 + 3] + qbi[e0 + 3];
  float k0 = (kv.x - muk) * rk * ksc[e0 + 0] + kbi[e0 + 0];
  float k1 = (kv.y - muk) * rk * ksc[e0 + 1] + kbi[e0 + 1];
  float k2 = (kv.z - muk) * rk * ksc[e0 + 2] + kbi[e0 + 2];
  float k3 = (kv.w - muk) * rk * ksc[e0 + 3] + kbi[e0 + 3];

  int p0 = d0 >> 1;
  float c0 = fcos[s * 32 + p0], s0 = fsin[s * 32 + p0];
  float c1 = fcos[s * 32 + p0 + 1], s1 = fsin[s * 32 + p0 + 1];
  float oq0 = q0 * c0 - q1 * s0, oq1 = q0 * s0 + q1 * c0;
  float oq2 = q2 * c1 - q3 * s1, oq3 = q2 * s1 + q3 * c1;
  float ok0 = k0 * c0 - k1 * s0, ok1 = k0 * s0 + k1 * c0;
  float ok2 = k2 * c1 - k3 * s1, ok3 = k2 * s1 + k3 * c1;

  const float QSC = 0.125f * 1.44269504088896340736f;  // 1/sqrt(64) * log2(e)
  u16x4v qo, ko;
  qo.x = f2bf(oq0 * QSC); qo.y = f2bf(oq1 * QSC);
  qo.z = f2bf(oq2 * QSC); qo.w = f2bf(oq3 * QSC);
  ko.x = f2bf(ok0); ko.y = f2bf(ok1); ko.z = f2bf(ok2); ko.w = f2bf(ok3);
  size_t base = ((size_t)(b * NH + h) * SEQ + s) * HD + d0;
  *(u16x4v*)(Q + base) = qo;
  *(u16x4v*)(Kk + base) = ko;
}

// ---- V transpose: Vt[b][h][d][s] bf16 from qkv fp32 ----
__global__ __launch_bounds__(256) void post_v(const float* __restrict__ qkv,
                                              u16* __restrict__ Vt) {
  __shared__ u16 vt[64][65];
  int bid = blockIdx.x;
  int st = bid & 31, bh = bid >> 5;
  int b = bh >> 4, h = bh & 15;
  int t = threadIdx.x;
#pragma unroll
  for (int i = 0; i < 16; ++i) {
    int idx = i * 256 + t;
    int ss = idx >> 6, d = idx & 63;
    float v = qkv[(size_t)(b * SEQ + st * 64 + ss) * 3072 + 2048 + h * 64 + d];
    vt[ss][d] = f2bf(v);
  }
  __syncthreads();
#pragma unroll
  for (int i = 0; i < 16; ++i) {
    int idx = i * 256 + t;
    int dd = idx >> 6, ss = idx & 63;
    Vt[((size_t)bh * 64 + dd) * SEQ + st * 64 + ss] = vt[ss][dd];
  }
}

// ---- flash attention v6: 2 q-sets per wave (32 q-rows) so each K/V LDS
//      fragment feeds 2 MFMAs (LDS-throughput was the binding pipe).
//      Proven round-3 sync skeleton: 2-buffer, __syncthreads full drain.
//      Swapped-QK^T in-register softmax, native exp2, setprio, XCD swizzle.
__global__ __launch_bounds__(256) void attn_fwd(const u16* __restrict__ Q,
                                                const u16* __restrict__ K,
                                                const u16* __restrict__ Vt,
                                                u16* __restrict__ O) {
  __shared__ u16 Ks[2][KVB * HD];  // [128 rows][64 cols]
  __shared__ u16 Vs[2][HD * KVB];  // [64 rows][128 cols]
  __shared__ u16 P[4][16][80];

  // XCD-aware bijective swizzle: nwg=512 -> each XCD owns 2 complete heads.
  int bid0 = blockIdx.x;
  int bid = (bid0 & 7) * 64 + (bid0 >> 3);
  int qb = bid & 15, bh = bid >> 4;
  int b = bh >> 4, h = bh & 15;
  int t = threadIdx.x;
  int w = t >> 6, lane = t & 63;
  int l15 = lane & 15, l4 = lane >> 4;
  int q0 = qb * 128 + w * 32;  // this wave: q-rows q0..q0+31 (2 sets of 16)
  const u16* Qh = Q + (size_t)bh * SEQ * HD;
  const u16* Kh = K + (size_t)bh * SEQ * HD;
  const u16* Vh = Vt + (size_t)bh * HD * SEQ;

  // staging: K tile 128x64 u16 = 1024 chunks(16B); V tile 64x128 = 1024.
  // 4 chunks each per thread. Linear LDS dest; source col pre-swizzled
  // (rule #21 both-sides XOR).
  const u16* Kg[4];
  const u16* Vg[4];
#pragma unroll
  for (int i = 0; i < 4; ++i) {
    int c = t + 256 * i;
    int kr = c >> 3, kcol = ((c & 7) ^ (kr & 7)) << 3;
    Kg[i] = Kh + (size_t)kr * HD + kcol;
    int vr = c >> 4, vcol = ((c & 15) ^ (vr & 7)) << 3;
    Vg[i] = Vh + (size_t)vr * SEQ + vcol;
  }

#define STAGE(tile, bufi)                                  \
  do {                                                     \
    size_t j0s = (size_t)(tile) * KVB;                     \
    gload16(Kg[0] + j0s * HD, &Ks[(bufi)][(t)*8]);         \
    gload16(Kg[1] + j0s * HD, &Ks[(bufi)][(t + 256) * 8]); \
    gload16(Kg[2] + j0s * HD, &Ks[(bufi)][(t + 512) * 8]); \
    gload16(Kg[3] + j0s * HD, &Ks[(bufi)][(t + 768) * 8]); \
    gload16(Vg[0] + j0s, &Vs[(bufi)][(t)*8]);              \
    gload16(Vg[1] + j0s, &Vs[(bufi)][(t + 256) * 8]);      \
    gload16(Vg[2] + j0s, &Vs[(bufi)][(t + 512) * 8]);      \
    gload16(Vg[3] + j0s, &Vs[(bufi)][(t + 768) * 8]);      \
  } while (0)

  // prologue: stage tile 0 into buf 0
  STAGE(0, 0);

  bf16x8 qf[2][2];
#pragma unroll
  for (int qs = 0; qs < 2; ++qs)
#pragma unroll
    for (int kf = 0; kf < 2; ++kf)
      qf[qs][kf] = *(const bf16x8*)(Qh + (size_t)(q0 + qs * 16 + l15) * HD +
                                    kf * 32 + l4 * 8);

  f32x4 oacc[2][4];
#pragma unroll
  for (int qs = 0; qs < 2; ++qs)
#pragma unroll
    for (int df = 0; df < 4; ++df) oacc[qs][df] = (f32x4){0.f, 0.f, 0.f, 0.f};
  float mrun[2] = {-1e30f, -1e30f};
  float lpart[2] = {0.f, 0.f};

  __syncthreads();  // full drain: tile 0 resident

// one softmax+PV phase: q-set qs, sacc half hb (0 or 4), V regs vf[2][4]
#define PHASE(qs, hb)                                                         \
  do {                                                                        \
    float rs = 0.f;                                                           \
    _Pragma("unroll") for (int j = 0; j < 4; ++j) {                           \
      float p0 = __builtin_amdgcn_exp2f(sacc[qs][(hb) + j][0] - mrun[qs]);    \
      float p1 = __builtin_amdgcn_exp2f(sacc[qs][(hb) + j][1] - mrun[qs]);    \
      float p2 = __builtin_amdgcn_exp2f(sacc[qs][(hb) + j][2] - mrun[qs]);    \
      float p3 = __builtin_amdgcn_exp2f(sacc[qs][(hb) + j][3] - mrun[qs]);    \
      rs += (p0 + p1) + (p2 + p3);                                            \
      __hip_bfloat162 pa, pb;                                                 \
      pa.x = __float2bfloat16(p0); pa.y = __float2bfloat16(p1);               \
      pb.x = __float2bfloat16(p2); pb.y = __float2bfloat16(p3);               \
      uint2 pk2;                                                              \
      pk2.x = *reinterpret_cast<unsigned int*>(&pa);                          \
      pk2.y = *reinterpret_cast<unsigned int*>(&pb);                          \
      *(uint2*)(&P[w][l15][j * 16 + l4 * 4]) = pk2;                           \
    }                                                                         \
    lpart[qs] += rs;                                                          \
    asm volatile("s_waitcnt lgkmcnt(0)" ::: "memory");                        \
    __builtin_amdgcn_sched_barrier(0);                                        \
    __builtin_amdgcn_s_setprio(1);                                            \
    _Pragma("unroll") for (int kc = 0; kc < 2; ++kc) {                        \
      bf16x8 pf = *(const bf16x8*)(&P[w][l15][kc * 32 + l4 * 8]);             \
      _Pragma("unroll") for (int df = 0; df < 4; ++df)                        \
        oacc[qs][df] = __builtin_amdgcn_mfma_f32_16x16x32_bf16(               \
            pf, vf[kc][df], oacc[qs][df], 0, 0, 0);                           \
    }                                                                         \
    __builtin_amdgcn_s_setprio(0);                                            \
  } while (0)

  int buf = 0;
  for (int it = 0; it < NT; ++it) {
    if (it + 1 < NT) STAGE(it + 1, buf ^ 1);  // flies under this tile's compute
    const u16* Kb_ = &Ks[buf][0];
    const u16* Vb_ = &Vs[buf][0];

    // QK^T swapped: each K fragment feeds BOTH q-sets (2 MFMA per LDS read)
    f32x4 sacc[2][8];
#pragma unroll
    for (int qs = 0; qs < 2; ++qs)
#pragma unroll
      for (int nf = 0; nf < 8; ++nf) sacc[qs][nf] = (f32x4){0.f, 0.f, 0.f, 0.f};
    __builtin_amdgcn_s_setprio(1);
#pragma unroll
    for (int nf = 0; nf < 8; ++nf) {
      int row = nf * 16 + l15;
      int swz = (row & 7) << 3;
#pragma unroll
      for (int kf = 0; kf < 2; ++kf) {
        bf16x8 kfr =
            *(const bf16x8*)(&Kb_[row * 64 + ((kf * 32 + l4 * 8) ^ swz)]);
        sacc[0][nf] =
            __builtin_amdgcn_mfma_f32_16x16x32_bf16(kfr, qf[0][kf], sacc[0][nf], 0, 0, 0);
        sacc[1][nf] =
            __builtin_amdgcn_mfma_f32_16x16x32_bf16(kfr, qf[1][kf], sacc[1][nf], 0, 0, 0);
      }
    }
    __builtin_amdgcn_s_setprio(0);

    // per-q-set row max (31 fmax + 2 shuffles each), defer-max (T13)
#pragma unroll
    for (int qs = 0; qs < 2; ++qs) {
      float mx = sacc[qs][0][0];
#pragma unroll
      for (int nf = 0; nf < 8; ++nf)
#pragma unroll
        for (int r = 0; r < 4; ++r) mx = fmaxf(mx, sacc[qs][nf][r]);
      mx = fmaxf(mx, __shfl_xor(mx, 16, 64));
      mx = fmaxf(mx, __shfl_xor(mx, 32, 64));
      if (!__all(mx - mrun[qs] <= 8.0f)) {
        float mnew = fmaxf(mrun[qs], mx);
        float scl = __builtin_amdgcn_exp2f(mrun[qs] - mnew);
        mrun[qs] = mnew;
        lpart[qs] *= scl;
        float sr[4];
#pragma unroll
        for (int r = 0; r < 4; ++r) sr[r] = __shfl(scl, l4 * 4 + r, 16);
#pragma unroll
        for (int df = 0; df < 4; ++df)
#pragma unroll
          for (int r = 0; r < 4; ++r) oacc[qs][df][r] *= sr[r];
      }
    }

    {
      // ---- half 0: V cols [0,64) ----
      bf16x8 vf[2][4];
#pragma unroll
      for (int df = 0; df < 4; ++df) {
        int row = df * 16 + l15;
        int swz = (row & 7) << 3;
#pragma unroll
        for (int kc = 0; kc < 2; ++kc)
          vf[kc][df] =
              *(const bf16x8*)(&Vb_[row * 128 + ((kc * 32 + l4 * 8) ^ swz)]);
      }
      PHASE(0, 0);
      PHASE(1, 0);
      // ---- half 1: V cols [64,128) (reuse vf registers) ----
#pragma unroll
      for (int df = 0; df < 4; ++df) {
        int row = df * 16 + l15;
        int swz = (row & 7) << 3;
#pragma unroll
        for (int kc = 0; kc < 2; ++kc)
          vf[kc][df] = *(const bf16x8*)(&Vb_[row * 128 +
                                             (((kc + 2) * 32 + l4 * 8) ^ swz)]);
      }
      PHASE(0, 4);
      PHASE(1, 4);
    }

    __syncthreads();  // full drain: next tile resident, all LDS ops done
    buf ^= 1;
  }
#undef PHASE
#undef STAGE
  // deferred l reduction + epilogue (both q-sets)
#pragma unroll
  for (int qs = 0; qs < 2; ++qs) {
    float lp = lpart[qs];
    lp += __shfl_xor(lp, 16, 64);
    lp += __shfl_xor(lp, 32, 64);
    float lr[4];
#pragma unroll
    for (int r = 0; r < 4; ++r) lr[r] = 1.0f / __shfl(lp, l4 * 4 + r, 16);
#pragma unroll
    for (int df = 0; df < 4; ++df) {
      int dcol = h * 64 + df * 16 + l15;
#pragma unroll
      for (int r = 0; r < 4; ++r)
        O[(size_t)(b * SEQ + q0 + qs * 16 + l4 * 4 + r) * DIM + dcol] =
            f2bf(oacc[qs][df][r] * lr[r]);
    }
  }
}

extern "C" void kernel_launch(void* const* d_in, const int* in_sizes, int n_in,
                              void* d_out, int out_size, void* d_ws,
                              size_t ws_size, hipStream_t stream) {
  const float* x = (const float*)d_in[0];
  const float* fsin = (const float*)d_in[1];
  const float* fcos = (const float*)d_in[2];
  const float* wq = (const float*)d_in[3];
  const float* wk = (const float*)d_in[4];
  const float* wv = (const float*)d_in[5];
  const float* wo = (const float*)d_in[6];
  const float* q_scale = (const float*)d_in[7];
  const float* q_bias = (const float*)d_in[8];
  const float* k_scale = (const float*)d_in[9];
  const float* k_bias = (const float*)d_in[10];
  float* out = (float*)d_out;

  u16* xb = (u16*)d_ws;                       // 4096*1024 bf16
  u16* wqkvT = xb + (size_t)ROWS * DIM;       // 3072*1024
  u16* woT = wqkvT + (size_t)3 * DIM * DIM;   // 1024*1024
  float* qkv = (float*)(woT + (size_t)DIM * DIM);  // 4096*3072 fp32
  u16* Qb = (u16*)(qkv + (size_t)ROWS * 3 * DIM);  // 32*2048*64
  u16* Kb = Qb + (size_t)BATCH * NH * SEQ * HD;
  u16* Vt = Kb + (size_t)BATCH * NH * SEQ * HD;
  u16* attnb = Vt + (size_t)BATCH * NH * SEQ * HD;  // 4096*1024

  prep<<<8192, 256, 0, stream>>>(x, wq, wk, wv, wo, xb, wqkvT, woT);
  gemm_bt<<<(ROWS / 128) * (3 * DIM / 128), 256, 0, stream>>>(xb, wqkvT, qkv,
                                                              ROWS, 3 * DIM, DIM);
  post_qk<<<ROWS, 256, 0, stream>>>(qkv, fsin, fcos, q_scale, q_bias, k_scale,
                                    k_bias, Qb, Kb);
  post_v<<<BATCH * NH * (SEQ / 64), 256, 0, stream>>>(qkv, Vt);
  attn_fwd<<<(BATCH * NH * SEQ) / 128, 256, 0, stream>>>(Qb, Kb, Vt, attnb);
  gemm_bt<<<(ROWS / 128) * (DIM / 128), 256, 0, stream>>>(attnb, woT, out, ROWS,
                                                          DIM, DIM);
}

// Round 9
// 243.271 us; speedup vs baseline: 1.1073x; 1.1073x over previous
//
#include <hip/hip_runtime.h>
#include <hip/hip_bf16.h>
#include <stddef.h>
#include <stdint.h>

#define DIM 1024
#define NH 16
#define HD 64
#define BATCH 2
#define SEQ 2048
#define ROWS (BATCH * SEQ) /* 4096 */
#define KVB 64
#define NT (SEQ / KVB) /* 32 */

typedef short bf16x8 __attribute__((ext_vector_type(8)));
typedef float f32x4 __attribute__((ext_vector_type(4)));
typedef float f32x16 __attribute__((ext_vector_type(16)));
typedef unsigned short u16;
typedef unsigned short u16x4v __attribute__((ext_vector_type(4)));

#define AS1 __attribute__((address_space(1)))
#define AS3 __attribute__((address_space(3)))

__device__ __forceinline__ void gload16(const u16* g, u16* l) {
  __builtin_amdgcn_global_load_lds((const AS1 void*)g, (AS3 void*)l, 16, 0, 0);
}

__device__ __forceinline__ u16 f2bf(float f) {
  union { float f; unsigned u; } v; v.f = f;
  unsigned r = v.u + 0x7FFFu + ((v.u >> 16) & 1u);
  return (u16)(r >> 16);
}

__device__ __forceinline__ unsigned pk2bf(float lo, float hi) {
  __hip_bfloat162 p;
  p.x = __float2bfloat16(lo);
  p.y = __float2bfloat16(hi);
  return *reinterpret_cast<unsigned*>(&p);
}

// ---- merged: convert x (fp32->bf16) [bid<4096] + weight transpose [bid>=4096]
__global__ __launch_bounds__(256) void prep(
    const float* __restrict__ x, const float* __restrict__ wq,
    const float* __restrict__ wk, const float* __restrict__ wv,
    const float* __restrict__ wo, u16* __restrict__ xb,
    u16* __restrict__ wqkvT, u16* __restrict__ woT) {
  __shared__ float tile[32][33];
  int bid = blockIdx.x;
  int t = threadIdx.x;
  if (bid < 4096) {
    int i = (bid * 256 + t) * 4;
    float4 v = *(const float4*)(x + i);
    u16x4v o;
    o.x = f2bf(v.x); o.y = f2bf(v.y); o.z = f2bf(v.z); o.w = f2bf(v.w);
    *(u16x4v*)(xb + i) = o;
  } else {
    int bb = bid - 4096;
    int mat = bb >> 10;
    int tIdx = bb & 1023;
    int tr = tIdx >> 5, tc = tIdx & 31;
    const float* src = mat == 0 ? wq : mat == 1 ? wk : mat == 2 ? wv : wo;
#pragma unroll
    for (int i = 0; i < 4; ++i) {
      int idx = i * 256 + t;
      int r = idx >> 5, c = idx & 31;
      tile[r][c] = src[(tr * 32 + r) * DIM + tc * 32 + c];
    }
    __syncthreads();
    u16* dst = (mat < 3) ? (wqkvT + mat * DIM * DIM) : woT;
#pragma unroll
    for (int i = 0; i < 4; ++i) {
      int idx = i * 256 + t;
      int r = idx >> 5, c = idx & 31;
      dst[(tc * 32 + r) * DIM + tr * 32 + c] = f2bf(tile[c][r]);
    }
  }
}

// ------- bf16 GEMM, B^T input (m97 structure: 128x128 tile, BK=32,
//         global_load_lds width-16, linear LDS) -------
__global__ __launch_bounds__(256) void gemm_bt(
    const u16* __restrict__ A, const u16* __restrict__ BT,
    float* __restrict__ C, int M, int N, int K) {
  __shared__ u16 As[128 * 32];
  __shared__ u16 Bs[128 * 32];
  int ntn = N >> 7;
  int tm = blockIdx.x / ntn, tn = blockIdx.x % ntn;
  int m0 = tm << 7, n0 = tn << 7;
  int t = threadIdx.x;
  int w = t >> 6, lane = t & 63;
  int l15 = lane & 15, l4 = lane >> 4;
  int wr = w >> 1, wc = w & 1;

  f32x4 acc[4][4];
#pragma unroll
  for (int i = 0; i < 4; ++i)
#pragma unroll
    for (int j = 0; j < 4; ++j) acc[i][j] = (f32x4){0.f, 0.f, 0.f, 0.f};

  int srow = t >> 2, scol = (t & 3) << 3;
  const u16* Ag = A + (size_t)(m0 + srow) * K + scol;
  const u16* Bg = BT + (size_t)(n0 + srow) * K + scol;
  u16* Asl = &As[t * 8];
  u16* Bsl = &Bs[t * 8];
  size_t half = (size_t)64 * K;

  for (int kt = 0; kt < K; kt += 32) {
    __syncthreads();
    gload16(Ag + kt, Asl);
    gload16(Ag + half + kt, Asl + 2048);
    gload16(Bg + kt, Bsl);
    gload16(Bg + half + kt, Bsl + 2048);
    __syncthreads();
    bf16x8 af[4], bfr[4];
#pragma unroll
    for (int i = 0; i < 4; ++i)
      af[i] = *(const bf16x8*)(&As[(wr * 64 + i * 16 + l15) * 32 + l4 * 8]);
#pragma unroll
    for (int j = 0; j < 4; ++j)
      bfr[j] = *(const bf16x8*)(&Bs[(wc * 64 + j * 16 + l15) * 32 + l4 * 8]);
#pragma unroll
    for (int i = 0; i < 4; ++i)
#pragma unroll
      for (int j = 0; j < 4; ++j)
        acc[i][j] = __builtin_amdgcn_mfma_f32_16x16x32_bf16(af[i], bfr[j],
                                                            acc[i][j], 0, 0, 0);
  }
#pragma unroll
  for (int i = 0; i < 4; ++i)
#pragma unroll
    for (int j = 0; j < 4; ++j) {
      int m = m0 + wr * 64 + i * 16 + l4 * 4;
      int n = n0 + wc * 64 + j * 16 + l15;
#pragma unroll
      for (int r = 0; r < 4; ++r) C[(size_t)(m + r) * N + n] = acc[i][j][r];
    }
}

// ---- LN + rotary for Q,K rows; emits bf16 Q,K in [b][h][s][d] ----
__global__ __launch_bounds__(256) void post_qk(
    const float* __restrict__ qkv, const float* __restrict__ fsin,
    const float* __restrict__ fcos, const float* __restrict__ qsc,
    const float* __restrict__ qbi, const float* __restrict__ ksc,
    const float* __restrict__ kbi, u16* __restrict__ Q, u16* __restrict__ Kk) {
  int row = blockIdx.x;  // b*SEQ + s
  int b = row >> 11, s = row & 2047;
  int t = threadIdx.x;
  const float* qrow = qkv + (size_t)row * 3072;
  const float* krow = qrow + DIM;
  float4 qv = *(const float4*)(qrow + t * 4);
  float4 kv = *(const float4*)(krow + t * 4);
  float qsum = qv.x + qv.y + qv.z + qv.w;
  float qss = qv.x * qv.x + qv.y * qv.y + qv.z * qv.z + qv.w * qv.w;
  float ksum = kv.x + kv.y + kv.z + kv.w;
  float kss = kv.x * kv.x + kv.y * kv.y + kv.z * kv.z + kv.w * kv.w;
#pragma unroll
  for (int off = 1; off < 64; off <<= 1) {
    qsum += __shfl_xor(qsum, off, 64);
    qss += __shfl_xor(qss, off, 64);
    ksum += __shfl_xor(ksum, off, 64);
    kss += __shfl_xor(kss, off, 64);
  }
  __shared__ float red[4][4];
  int w = t >> 6;
  if ((t & 63) == 0) {
    red[w][0] = qsum; red[w][1] = qss; red[w][2] = ksum; red[w][3] = kss;
  }
  __syncthreads();
  qsum = red[0][0] + red[1][0] + red[2][0] + red[3][0];
  qss = red[0][1] + red[1][1] + red[2][1] + red[3][1];
  ksum = red[0][2] + red[1][2] + red[2][2] + red[3][2];
  kss = red[0][3] + red[1][3] + red[2][3] + red[3][3];
  const float inv = 1.0f / 1024.0f;
  float muq = qsum * inv;
  float rq = rsqrtf(qss * inv - muq * muq + 1e-6f);
  float muk = ksum * inv;
  float rk = rsqrtf(kss * inv - muk * muk + 1e-6f);

  int e0 = t * 4;
  int h = e0 >> 6, d0 = e0 & 63;
  float q0 = (qv.x - muq) * rq * qsc[e0 + 0] + qbi[e0 + 0];
  float q1 = (qv.y - muq) * rq * qsc[e0 + 1] + qbi[e0 + 1];
  float q2 = (qv.z - muq) * rq * qsc[e0 + 2] + qbi[e0 + 2];
  float q3 = (qv.w - muq) * rq * qsc[e0 + 3] + qbi[e0 + 3];
  float k0 = (kv.x - muk) * rk * ksc[e0 + 0] + kbi[e0 + 0];
  float k1 = (kv.y - muk) * rk * ksc[e0 + 1] + kbi[e0 + 1];
  float k2 = (kv.z - muk) * rk * ksc[e0 + 2] + kbi[e0 + 2];
  float k3 = (kv.w - muk) * rk * ksc[e0 + 3] + kbi[e0 + 3];

  int p0 = d0 >> 1;
  float c0 = fcos[s * 32 + p0], s0 = fsin[s * 32 + p0];
  float c1 = fcos[s * 32 + p0 + 1], s1 = fsin[s * 32 + p0 + 1];
  float oq0 = q0 * c0 - q1 * s0, oq1 = q0 * s0 + q1 * c0;
  float oq2 = q2 * c1 - q3 * s1, oq3 = q2 * s1 + q3 * c1;
  float ok0 = k0 * c0 - k1 * s0, ok1 = k0 * s0 + k1 * c0;
  float ok2 = k2 * c1 - k3 * s1, ok3 = k2 * s1 + k3 * c1;

  const float QSC = 0.125f * 1.44269504088896340736f;  // 1/sqrt(64) * log2(e)
  u16x4v qo, ko;
  qo.x = f2bf(oq0 * QSC); qo.y = f2bf(oq1 * QSC);
  qo.z = f2bf(oq2 * QSC); qo.w = f2bf(oq3 * QSC);
  ko.x = f2bf(ok0); ko.y = f2bf(ok1); ko.z = f2bf(ok2); ko.w = f2bf(ok3);
  size_t base = ((size_t)(b * NH + h) * SEQ + s) * HD + d0;
  *(u16x4v*)(Q + base) = qo;
  *(u16x4v*)(Kk + base) = ko;
}

// ---- V transpose: Vt[b][h][d][s] bf16 from qkv fp32 ----
__global__ __launch_bounds__(256) void post_v(const float* __restrict__ qkv,
                                              u16* __restrict__ Vt) {
  __shared__ u16 vt[64][65];
  int bid = blockIdx.x;
  int st = bid & 31, bh = bid >> 5;
  int b = bh >> 4, h = bh & 15;
  int t = threadIdx.x;
#pragma unroll
  for (int i = 0; i < 16; ++i) {
    int idx = i * 256 + t;
    int ss = idx >> 6, d = idx & 63;
    float v = qkv[(size_t)(b * SEQ + st * 64 + ss) * 3072 + 2048 + h * 64 + d];
    vt[ss][d] = f2bf(v);
  }
  __syncthreads();
#pragma unroll
  for (int i = 0; i < 16; ++i) {
    int idx = i * 256 + t;
    int dd = idx >> 6, ss = idx & 63;
    Vt[((size_t)bh * 64 + dd) * SEQ + st * 64 + ss] = vt[ss][dd];
  }
}

// ---- flash attention v7: 32x32 MFMA, fully in-register softmax+P (T12:
//      cvt_pk pairs + v_permlane32_swap -> PV A-frags; ZERO P LDS traffic).
//      Swapped QK^T: S^T col=q=lane&31, row=key=(reg&3)+8(reg>>2)+4(lane>>5).
//      Proven 2-buffer __syncthreads skeleton, KVB=64, XCD swizzle, T13.
__global__ __launch_bounds__(256) void attn_fwd(const u16* __restrict__ Q,
                                                const u16* __restrict__ K,
                                                const u16* __restrict__ Vt,
                                                u16* __restrict__ O) {
  __shared__ u16 Ks[2][KVB * HD];  // [64 keys][64 d]
  __shared__ u16 Vs[2][HD * KVB];  // [64 d][64 s]

  // XCD-aware bijective swizzle: nwg=512 -> each XCD owns 2 complete heads.
  int bid0 = blockIdx.x;
  int bid = (bid0 & 7) * 64 + (bid0 >> 3);
  int qb = bid & 15, bh = bid >> 4;  // qb: 16 q-blocks of 128 rows
  int b = bh >> 4, h = bh & 15;
  int t = threadIdx.x;
  int w = t >> 6, lane = t & 63;
  int l31 = lane & 31, hi = lane >> 5;
  int q0 = qb * 128 + w * 32;  // this wave: q-rows q0..q0+31
  const u16* Qh = Q + (size_t)bh * SEQ * HD;
  const u16* Kh = K + (size_t)bh * SEQ * HD;
  const u16* Vh = Vt + (size_t)bh * HD * SEQ;

  // staging: K tile 64x64 u16 = 512 chunks(16B), V same; 2+2 per thread.
  // Linear LDS dest; source col pre-swizzled (rule #21 both-sides XOR).
  const u16* Kg[2];
  const u16* Vg[2];
#pragma unroll
  for (int i = 0; i < 2; ++i) {
    int c = t + 256 * i;
    int r = c >> 3, col = ((c & 7) ^ (r & 7)) << 3;
    Kg[i] = Kh + (size_t)r * HD + col;
    Vg[i] = Vh + (size_t)r * SEQ + col;
  }

#define STAGE(tile, bufi)                                \
  do {                                                   \
    size_t j0s = (size_t)(tile) * KVB;                   \
    gload16(Kg[0] + j0s * HD, &Ks[(bufi)][(t)*8]);       \
    gload16(Kg[1] + j0s * HD, &Ks[(bufi)][(t + 256) * 8]); \
    gload16(Vg[0] + j0s, &Vs[(bufi)][(t)*8]);            \
    gload16(Vg[1] + j0s, &Vs[(bufi)][(t + 256) * 8]);    \
  } while (0)

  STAGE(0, 0);

  // Q B-frags: col=q=l31, k=d = ds*16 + hi*8 + e (4 d-steps cover d=64)
  bf16x8 qf[4];
#pragma unroll
  for (int ds = 0; ds < 4; ++ds)
    qf[ds] = *(const bf16x8*)(Qh + (size_t)(q0 + l31) * HD + ds * 16 + hi * 8);

  f32x16 oacc[2];
#pragma unroll
  for (int db = 0; db < 2; ++db)
#pragma unroll
    for (int r = 0; r < 16; ++r) oacc[db][r] = 0.f;
  float mrun = -1e30f, lpart = 0.f;
  int hi4 = hi << 2;  // row offset of this half in the C/D map

  __syncthreads();  // full drain: tile 0 resident

  int buf = 0;
  for (int it = 0; it < NT; ++it) {
    if (it + 1 < NT) STAGE(it + 1, buf ^ 1);  // flies under this tile's compute
    const u16* Kb_ = &Ks[buf][0];
    const u16* Vb_ = &Vs[buf][0];

#pragma unroll
    for (int kb = 0; kb < 2; ++kb) {  // two 32-key blocks per tile
      // ---- QK^T: S^T[key][q], A=K (row=key=l31, k=d), B=Q ----
      f32x16 sacc;
#pragma unroll
      for (int r = 0; r < 16; ++r) sacc[r] = 0.f;
      int krow = kb * 32 + l31;
      int kswz = (krow & 7) << 3;
      __builtin_amdgcn_s_setprio(1);
#pragma unroll
      for (int ds = 0; ds < 4; ++ds) {
        bf16x8 kfr =
            *(const bf16x8*)(&Kb_[krow * 64 + ((ds * 16 + hi * 8) ^ kswz)]);
        sacc = __builtin_amdgcn_mfma_f32_32x32x16_bf16(kfr, qf[ds], sacc, 0, 0, 0);
      }
      __builtin_amdgcn_s_setprio(0);

      // ---- row max: 15 fmax + ONE shfl (lane<->lane+32) ----
      float mx = sacc[0];
#pragma unroll
      for (int r = 1; r < 16; ++r) mx = fmaxf(mx, sacc[r]);
      mx = fmaxf(mx, __shfl_xor(mx, 32, 64));
      // defer-max (T13)
      if (!__all(mx - mrun <= 8.0f)) {
        float mnew = fmaxf(mrun, mx);
        float scl = __builtin_amdgcn_exp2f(mrun - mnew);
        mrun = mnew;
        lpart *= scl;
#pragma unroll
        for (int r = 0; r < 16; ++r) {
          int crow = (r & 3) + ((r >> 2) << 3) + hi4;
          float sq = __shfl(scl, crow, 32);
          oacc[0][r] *= sq;
          oacc[1][r] *= sq;
        }
      }

      // ---- p = exp2(s - m), per-lane partial rowsum ----
      float p[16];
      float rs = 0.f;
#pragma unroll
      for (int r = 0; r < 16; ++r) {
        p[r] = __builtin_amdgcn_exp2f(sacc[r] - mrun);
        rs += p[r];
      }
      lpart += rs;

      // ---- PV: per 16-key step, build A-frag in-register (T12) ----
#pragma unroll
      for (int st = 0; st < 2; ++st) {
        int bs = st * 8;
        unsigned w01 = pk2bf(p[bs + 0], p[bs + 1]);
        unsigned w45 = pk2bf(p[bs + 4], p[bs + 5]);
        asm("v_permlane32_swap_b32 %0, %1" : "+v"(w01), "+v"(w45));
        unsigned w23 = pk2bf(p[bs + 2], p[bs + 3]);
        unsigned w67 = pk2bf(p[bs + 6], p[bs + 7]);
        asm("v_permlane32_swap_b32 %0, %1" : "+v"(w23), "+v"(w67));
        union { unsigned u[4]; bf16x8 v; } pa;
        pa.u[0] = w01; pa.u[1] = w23; pa.u[2] = w45; pa.u[3] = w67;
        __builtin_amdgcn_s_setprio(1);
#pragma unroll
        for (int db = 0; db < 2; ++db) {
          int vrow = db * 32 + l31;
          int vswz = (vrow & 7) << 3;
          bf16x8 vfr = *(const bf16x8*)(&Vb_[vrow * 64 +
              ((kb * 32 + st * 16 + hi * 8) ^ vswz)]);
          oacc[db] =
              __builtin_amdgcn_mfma_f32_32x32x16_bf16(pa.v, vfr, oacc[db], 0, 0, 0);
        }
        __builtin_amdgcn_s_setprio(0);
      }
    }

    __syncthreads();  // full drain: next tile resident, all LDS reads done
    buf ^= 1;
  }
#undef STAGE

  // ---- epilogue: l reduction + normalize + store ----
  float lsum = lpart + __shfl_xor(lpart, 32, 64);
  float rl = 1.0f / lsum;  // reciprocal for q = l31 (this lane's column q)
#pragma unroll
  for (int r = 0; r < 16; ++r) {
    int crow = (r & 3) + ((r >> 2) << 3) + hi4;
    float lr = __shfl(rl, crow, 32);
    int orow = q0 + crow;
#pragma unroll
    for (int db = 0; db < 2; ++db) {
      int dcol = h * 64 + db * 32 + l31;
      O[(size_t)(b * SEQ + orow) * DIM + dcol] = f2bf(oacc[db][r] * lr);
    }
  }
}

extern "C" void kernel_launch(void* const* d_in, const int* in_sizes, int n_in,
                              void* d_out, int out_size, void* d_ws,
                              size_t ws_size, hipStream_t stream) {
  const float* x = (const float*)d_in[0];
  const float* fsin = (const float*)d_in[1];
  const float* fcos = (const float*)d_in[2];
  const float* wq = (const float*)d_in[3];
  const float* wk = (const float*)d_in[4];
  const float* wv = (const float*)d_in[5];
  const float* wo = (const float*)d_in[6];
  const float* q_scale = (const float*)d_in[7];
  const float* q_bias = (const float*)d_in[8];
  const float* k_scale = (const float*)d_in[9];
  const float* k_bias = (const float*)d_in[10];
  float* out = (float*)d_out;

  u16* xb = (u16*)d_ws;                       // 4096*1024 bf16
  u16* wqkvT = xb + (size_t)ROWS * DIM;       // 3072*1024
  u16* woT = wqkvT + (size_t)3 * DIM * DIM;   // 1024*1024
  float* qkv = (float*)(woT + (size_t)DIM * DIM);  // 4096*3072 fp32
  u16* Qb = (u16*)(qkv + (size_t)ROWS * 3 * DIM);  // 32*2048*64
  u16* Kb = Qb + (size_t)BATCH * NH * SEQ * HD;
  u16* Vt = Kb + (size_t)BATCH * NH * SEQ * HD;
  u16* attnb = Vt + (size_t)BATCH * NH * SEQ * HD;  // 4096*1024

  prep<<<8192, 256, 0, stream>>>(x, wq, wk, wv, wo, xb, wqkvT, woT);
  gemm_bt<<<(ROWS / 128) * (3 * DIM / 128), 256, 0, stream>>>(xb, wqkvT, qkv,
                                                              ROWS, 3 * DIM, DIM);
  post_qk<<<ROWS, 256, 0, stream>>>(qkv, fsin, fcos, q_scale, q_bias, k_scale,
                                    k_bias, Qb, Kb);
  post_v<<<BATCH * NH * (SEQ / 64), 256, 0, stream>>>(qkv, Vt);
  attn_fwd<<<(BATCH * NH * SEQ) / 128, 256, 0, stream>>>(Qb, Kb, Vt, attnb);
  gemm_bt<<<(ROWS / 128) * (DIM / 128), 256, 0, stream>>>(attnb, woT, out, ROWS,
                                                          DIM, DIM);
}

// Round 10
// 228.210 us; speedup vs baseline: 1.1804x; 1.0660x over previous
//
#include <hip/hip_runtime.h>
#include <hip/hip_bf16.h>
#include <stddef.h>
#include <stdint.h>

#define DIM 1024
#define NH 16
#define HD 64
#define BATCH 2
#define SEQ 2048
#define ROWS (BATCH * SEQ) /* 4096 */
#define KVB 64
#define NT (SEQ / KVB) /* 32 */

typedef short bf16x8 __attribute__((ext_vector_type(8)));
typedef float f32x4 __attribute__((ext_vector_type(4)));
typedef float f32x16 __attribute__((ext_vector_type(16)));
typedef unsigned short u16;
typedef unsigned short u16x4v __attribute__((ext_vector_type(4)));

#define AS1 __attribute__((address_space(1)))
#define AS3 __attribute__((address_space(3)))

__device__ __forceinline__ void gload16(const u16* g, u16* l) {
  __builtin_amdgcn_global_load_lds((const AS1 void*)g, (AS3 void*)l, 16, 0, 0);
}

__device__ __forceinline__ u16 f2bf(float f) {
  union { float f; unsigned u; } v; v.f = f;
  unsigned r = v.u + 0x7FFFu + ((v.u >> 16) & 1u);
  return (u16)(r >> 16);
}

__device__ __forceinline__ float bf2f(u16 h) {
  union { unsigned u; float f; } v;
  v.u = ((unsigned)h) << 16;
  return v.f;
}

__device__ __forceinline__ unsigned pk2bf(float lo, float hi) {
  __hip_bfloat162 p;
  p.x = __float2bfloat16(lo);
  p.y = __float2bfloat16(hi);
  return *reinterpret_cast<unsigned*>(&p);
}

// ---- merged: convert x (fp32->bf16) [bid<4096] + weight transpose [bid>=4096]
__global__ __launch_bounds__(256) void prep(
    const float* __restrict__ x, const float* __restrict__ wq,
    const float* __restrict__ wk, const float* __restrict__ wv,
    const float* __restrict__ wo, u16* __restrict__ xb,
    u16* __restrict__ wqkvT, u16* __restrict__ woT) {
  __shared__ float tile[32][33];
  int bid = blockIdx.x;
  int t = threadIdx.x;
  if (bid < 4096) {
    int i = (bid * 256 + t) * 4;
    float4 v = *(const float4*)(x + i);
    u16x4v o;
    o.x = f2bf(v.x); o.y = f2bf(v.y); o.z = f2bf(v.z); o.w = f2bf(v.w);
    *(u16x4v*)(xb + i) = o;
  } else {
    int bb = bid - 4096;
    int mat = bb >> 10;
    int tIdx = bb & 1023;
    int tr = tIdx >> 5, tc = tIdx & 31;
    const float* src = mat == 0 ? wq : mat == 1 ? wk : mat == 2 ? wv : wo;
#pragma unroll
    for (int i = 0; i < 4; ++i) {
      int idx = i * 256 + t;
      int r = idx >> 5, c = idx & 31;
      tile[r][c] = src[(tr * 32 + r) * DIM + tc * 32 + c];
    }
    __syncthreads();
    u16* dst = (mat < 3) ? (wqkvT + mat * DIM * DIM) : woT;
#pragma unroll
    for (int i = 0; i < 4; ++i) {
      int idx = i * 256 + t;
      int r = idx >> 5, c = idx & 31;
      dst[(tc * 32 + r) * DIM + tr * 32 + c] = f2bf(tile[c][r]);
    }
  }
}

// ------- bf16 GEMM, B^T input (m97 structure: 128x128 tile, BK=32,
//         global_load_lds width-16, linear LDS). BF16OUT: bf16 C. -------
template <bool BF16OUT>
__global__ __launch_bounds__(256) void gemm_bt(
    const u16* __restrict__ A, const u16* __restrict__ BT,
    void* __restrict__ Cv, int M, int N, int K) {
  __shared__ u16 As[128 * 32];
  __shared__ u16 Bs[128 * 32];
  int ntn = N >> 7;
  int tm = blockIdx.x / ntn, tn = blockIdx.x % ntn;
  int m0 = tm << 7, n0 = tn << 7;
  int t = threadIdx.x;
  int w = t >> 6, lane = t & 63;
  int l15 = lane & 15, l4 = lane >> 4;
  int wr = w >> 1, wc = w & 1;

  f32x4 acc[4][4];
#pragma unroll
  for (int i = 0; i < 4; ++i)
#pragma unroll
    for (int j = 0; j < 4; ++j) acc[i][j] = (f32x4){0.f, 0.f, 0.f, 0.f};

  int srow = t >> 2, scol = (t & 3) << 3;
  const u16* Ag = A + (size_t)(m0 + srow) * K + scol;
  const u16* Bg = BT + (size_t)(n0 + srow) * K + scol;
  u16* Asl = &As[t * 8];
  u16* Bsl = &Bs[t * 8];
  size_t half = (size_t)64 * K;

  for (int kt = 0; kt < K; kt += 32) {
    __syncthreads();
    gload16(Ag + kt, Asl);
    gload16(Ag + half + kt, Asl + 2048);
    gload16(Bg + kt, Bsl);
    gload16(Bg + half + kt, Bsl + 2048);
    __syncthreads();
    bf16x8 af[4], bfr[4];
#pragma unroll
    for (int i = 0; i < 4; ++i)
      af[i] = *(const bf16x8*)(&As[(wr * 64 + i * 16 + l15) * 32 + l4 * 8]);
#pragma unroll
    for (int j = 0; j < 4; ++j)
      bfr[j] = *(const bf16x8*)(&Bs[(wc * 64 + j * 16 + l15) * 32 + l4 * 8]);
#pragma unroll
    for (int i = 0; i < 4; ++i)
#pragma unroll
      for (int j = 0; j < 4; ++j)
        acc[i][j] = __builtin_amdgcn_mfma_f32_16x16x32_bf16(af[i], bfr[j],
                                                            acc[i][j], 0, 0, 0);
  }
#pragma unroll
  for (int i = 0; i < 4; ++i)
#pragma unroll
    for (int j = 0; j < 4; ++j) {
      int m = m0 + wr * 64 + i * 16 + l4 * 4;
      int n = n0 + wc * 64 + j * 16 + l15;
#pragma unroll
      for (int r = 0; r < 4; ++r) {
        if constexpr (BF16OUT) {
          ((u16*)Cv)[(size_t)(m + r) * N + n] = f2bf(acc[i][j][r]);
        } else {
          ((float*)Cv)[(size_t)(m + r) * N + n] = acc[i][j][r];
        }
      }
    }
}

// ---- LN + rotary for Q,K rows (bf16 qkv in); emits bf16 Q,K [b][h][s][d] ----
__global__ __launch_bounds__(256) void post_qk(
    const u16* __restrict__ qkv, const float* __restrict__ fsin,
    const float* __restrict__ fcos, const float* __restrict__ qsc,
    const float* __restrict__ qbi, const float* __restrict__ ksc,
    const float* __restrict__ kbi, u16* __restrict__ Q, u16* __restrict__ Kk) {
  int row = blockIdx.x;  // b*SEQ + s
  int b = row >> 11, s = row & 2047;
  int t = threadIdx.x;
  const u16* qrow = qkv + (size_t)row * 3072;
  const u16* krow = qrow + DIM;
  u16x4v qu = *(const u16x4v*)(qrow + t * 4);
  u16x4v ku = *(const u16x4v*)(krow + t * 4);
  float qv[4] = {bf2f(qu.x), bf2f(qu.y), bf2f(qu.z), bf2f(qu.w)};
  float kv[4] = {bf2f(ku.x), bf2f(ku.y), bf2f(ku.z), bf2f(ku.w)};
  float qsum = qv[0] + qv[1] + qv[2] + qv[3];
  float qss = qv[0] * qv[0] + qv[1] * qv[1] + qv[2] * qv[2] + qv[3] * qv[3];
  float ksum = kv[0] + kv[1] + kv[2] + kv[3];
  float kss = kv[0] * kv[0] + kv[1] * kv[1] + kv[2] * kv[2] + kv[3] * kv[3];
#pragma unroll
  for (int off = 1; off < 64; off <<= 1) {
    qsum += __shfl_xor(qsum, off, 64);
    qss += __shfl_xor(qss, off, 64);
    ksum += __shfl_xor(ksum, off, 64);
    kss += __shfl_xor(kss, off, 64);
  }
  __shared__ float red[4][4];
  int w = t >> 6;
  if ((t & 63) == 0) {
    red[w][0] = qsum; red[w][1] = qss; red[w][2] = ksum; red[w][3] = kss;
  }
  __syncthreads();
  qsum = red[0][0] + red[1][0] + red[2][0] + red[3][0];
  qss = red[0][1] + red[1][1] + red[2][1] + red[3][1];
  ksum = red[0][2] + red[1][2] + red[2][2] + red[3][2];
  kss = red[0][3] + red[1][3] + red[2][3] + red[3][3];
  const float inv = 1.0f / 1024.0f;
  float muq = qsum * inv;
  float rq = rsqrtf(qss * inv - muq * muq + 1e-6f);
  float muk = ksum * inv;
  float rk = rsqrtf(kss * inv - muk * muk + 1e-6f);

  int e0 = t * 4;
  int h = e0 >> 6, d0 = e0 & 63;
  float q0 = (qv[0] - muq) * rq * qsc[e0 + 0] + qbi[e0 + 0];
  float q1 = (qv[1] - muq) * rq * qsc[e0 + 1] + qbi[e0 + 1];
  float q2 = (qv[2] - muq) * rq * qsc[e0 + 2] + qbi[e0 + 2];
  float q3 = (qv[3] - muq) * rq * qsc[e0 + 3] + qbi[e0 + 3];
  float k0 = (kv[0] - muk) * rk * ksc[e0 + 0] + kbi[e0 + 0];
  float k1 = (kv[1] - muk) * rk * ksc[e0 + 1] + kbi[e0 + 1];
  float k2 = (kv[2] - muk) * rk * ksc[e0 + 2] + kbi[e0 + 2];
  float k3 = (kv[3] - muk) * rk * ksc[e0 + 3] + kbi[e0 + 3];

  int p0 = d0 >> 1;
  float c0 = fcos[s * 32 + p0], s0 = fsin[s * 32 + p0];
  float c1 = fcos[s * 32 + p0 + 1], s1 = fsin[s * 32 + p0 + 1];
  float oq0 = q0 * c0 - q1 * s0, oq1 = q0 * s0 + q1 * c0;
  float oq2 = q2 * c1 - q3 * s1, oq3 = q2 * s1 + q3 * c1;
  float ok0 = k0 * c0 - k1 * s0, ok1 = k0 * s0 + k1 * c0;
  float ok2 = k2 * c1 - k3 * s1, ok3 = k2 * s1 + k3 * c1;

  const float QSC = 0.125f * 1.44269504088896340736f;  // 1/sqrt(64) * log2(e)
  u16x4v qo, ko;
  qo.x = f2bf(oq0 * QSC); qo.y = f2bf(oq1 * QSC);
  qo.z = f2bf(oq2 * QSC); qo.w = f2bf(oq3 * QSC);
  ko.x = f2bf(ok0); ko.y = f2bf(ok1); ko.z = f2bf(ok2); ko.w = f2bf(ok3);
  size_t base = ((size_t)(b * NH + h) * SEQ + s) * HD + d0;
  *(u16x4v*)(Q + base) = qo;
  *(u16x4v*)(Kk + base) = ko;
}

// ---- V transpose: Vt[b][h][d][s] from bf16 qkv (pure u16 shuffle) ----
__global__ __launch_bounds__(256) void post_v(const u16* __restrict__ qkv,
                                              u16* __restrict__ Vt) {
  __shared__ u16 vt[64][65];
  int bid = blockIdx.x;
  int st = bid & 31, bh = bid >> 5;
  int b = bh >> 4, h = bh & 15;
  int t = threadIdx.x;
#pragma unroll
  for (int i = 0; i < 16; ++i) {
    int idx = i * 256 + t;
    int ss = idx >> 6, d = idx & 63;
    vt[ss][d] = qkv[(size_t)(b * SEQ + st * 64 + ss) * 3072 + 2048 + h * 64 + d];
  }
  __syncthreads();
#pragma unroll
  for (int i = 0; i < 16; ++i) {
    int idx = i * 256 + t;
    int dd = idx >> 6, ss = idx & 63;
    Vt[((size_t)bh * 64 + dd) * SEQ + st * 64 + ss] = vt[ss][dd];
  }
}

// ---- flash attention v8: 32x32 MFMA + in-register softmax/P (T12),
//      NO max tracking (Q is LN'd + pre-scaled: |s|<~10 in log2 domain,
//      exp2 safely in fp32/bf16 range), 128-thread blocks (grid 1024 ->
//      4 blocks/CU; was grid-limited at 2), 2-buffer __syncthreads skeleton.
__global__ __launch_bounds__(128) void attn_fwd(const u16* __restrict__ Q,
                                                const u16* __restrict__ K,
                                                const u16* __restrict__ Vt,
                                                u16* __restrict__ O) {
  __shared__ u16 Ks[2][KVB * HD];  // [64 keys][64 d]
  __shared__ u16 Vs[2][HD * KVB];  // [64 d][64 s]

  // XCD-aware bijective swizzle: nwg=1024 -> each XCD owns 4 complete heads.
  int bid0 = blockIdx.x;
  int bid = (bid0 & 7) * 128 + (bid0 >> 3);
  int qb = bid & 31, bh = bid >> 5;  // 32 q-blocks of 64 rows
  int b = bh >> 4, h = bh & 15;
  int t = threadIdx.x;
  int w = t >> 6, lane = t & 63;
  int l31 = lane & 31, hi = lane >> 5;
  int q0 = qb * 64 + w * 32;  // this wave: q-rows q0..q0+31
  const u16* Qh = Q + (size_t)bh * SEQ * HD;
  const u16* Kh = K + (size_t)bh * SEQ * HD;
  const u16* Vh = Vt + (size_t)bh * HD * SEQ;

  // staging: K tile 64x64 u16 = 512 16B-chunks, V same; 4+4 per thread.
  // Linear LDS dest; source col pre-swizzled (rule #21 both-sides XOR).
  const u16* Kg[4];
  const u16* Vg[4];
#pragma unroll
  for (int i = 0; i < 4; ++i) {
    int c = t + 128 * i;
    int r = c >> 3, col = ((c & 7) ^ (r & 7)) << 3;
    Kg[i] = Kh + (size_t)r * HD + col;
    Vg[i] = Vh + (size_t)r * SEQ + col;
  }

#define STAGE(tile, bufi)                                    \
  do {                                                       \
    size_t j0s = (size_t)(tile) * KVB;                       \
    gload16(Kg[0] + j0s * HD, &Ks[(bufi)][(t)*8]);           \
    gload16(Kg[1] + j0s * HD, &Ks[(bufi)][(t + 128) * 8]);   \
    gload16(Kg[2] + j0s * HD, &Ks[(bufi)][(t + 256) * 8]);   \
    gload16(Kg[3] + j0s * HD, &Ks[(bufi)][(t + 384) * 8]);   \
    gload16(Vg[0] + j0s, &Vs[(bufi)][(t)*8]);                \
    gload16(Vg[1] + j0s, &Vs[(bufi)][(t + 128) * 8]);        \
    gload16(Vg[2] + j0s, &Vs[(bufi)][(t + 256) * 8]);        \
    gload16(Vg[3] + j0s, &Vs[(bufi)][(t + 384) * 8]);        \
  } while (0)

  STAGE(0, 0);

  // Q B-frags: col=q=l31, k=d = ds*16 + hi*8 + e (4 d-steps cover d=64)
  bf16x8 qf[4];
#pragma unroll
  for (int ds = 0; ds < 4; ++ds)
    qf[ds] = *(const bf16x8*)(Qh + (size_t)(q0 + l31) * HD + ds * 16 + hi * 8);

  f32x16 oacc[2];
#pragma unroll
  for (int db = 0; db < 2; ++db)
#pragma unroll
    for (int r = 0; r < 16; ++r) oacc[db][r] = 0.f;
  float lpart = 0.f;
  int hi4 = hi << 2;

  __syncthreads();  // full drain: tile 0 resident

  int buf = 0;
  for (int it = 0; it < NT; ++it) {
    if (it + 1 < NT) STAGE(it + 1, buf ^ 1);  // flies under this tile's compute
    const u16* Kb_ = &Ks[buf][0];
    const u16* Vb_ = &Vs[buf][0];

#pragma unroll
    for (int kb = 0; kb < 2; ++kb) {  // two 32-key blocks per tile
      // ---- QK^T: S^T[key][q], A=K (row=key=l31, k=d), B=Q ----
      f32x16 sacc;
#pragma unroll
      for (int r = 0; r < 16; ++r) sacc[r] = 0.f;
      int krow = kb * 32 + l31;
      int kswz = (krow & 7) << 3;
      __builtin_amdgcn_s_setprio(1);
#pragma unroll
      for (int ds = 0; ds < 4; ++ds) {
        bf16x8 kfr =
            *(const bf16x8*)(&Kb_[krow * 64 + ((ds * 16 + hi * 8) ^ kswz)]);
        sacc = __builtin_amdgcn_mfma_f32_32x32x16_bf16(kfr, qf[ds], sacc, 0, 0, 0);
      }
      __builtin_amdgcn_s_setprio(0);

      // ---- p = exp2(s) (no max subtraction), per-lane partial rowsum ----
      float p[16];
      float rs = 0.f;
#pragma unroll
      for (int r = 0; r < 16; ++r) {
        p[r] = __builtin_amdgcn_exp2f(sacc[r]);
        rs += p[r];
      }
      lpart += rs;

      // ---- PV: per 16-key step, build A-frag in-register (T12) ----
#pragma unroll
      for (int st = 0; st < 2; ++st) {
        int bs = st * 8;
        unsigned w01 = pk2bf(p[bs + 0], p[bs + 1]);
        unsigned w45 = pk2bf(p[bs + 4], p[bs + 5]);
        asm("v_permlane32_swap_b32 %0, %1" : "+v"(w01), "+v"(w45));
        unsigned w23 = pk2bf(p[bs + 2], p[bs + 3]);
        unsigned w67 = pk2bf(p[bs + 6], p[bs + 7]);
        asm("v_permlane32_swap_b32 %0, %1" : "+v"(w23), "+v"(w67));
        union { unsigned u[4]; bf16x8 v; } pa;
        pa.u[0] = w01; pa.u[1] = w23; pa.u[2] = w45; pa.u[3] = w67;
        __builtin_amdgcn_s_setprio(1);
#pragma unroll
        for (int db = 0; db < 2; ++db) {
          int vrow = db * 32 + l31;
          int vswz = (vrow & 7) << 3;
          bf16x8 vfr = *(const bf16x8*)(&Vb_[vrow * 64 +
              ((kb * 32 + st * 16 + hi * 8) ^ vswz)]);
          oacc[db] =
              __builtin_amdgcn_mfma_f32_32x32x16_bf16(pa.v, vfr, oacc[db], 0, 0, 0);
        }
        __builtin_amdgcn_s_setprio(0);
      }
    }

    __syncthreads();  // full drain: next tile resident, all LDS reads done
    buf ^= 1;
  }
#undef STAGE

  // ---- epilogue: l reduction + normalize + store ----
  float lsum = lpart + __shfl_xor(lpart, 32, 64);
  float rl = 1.0f / lsum;  // for q-column l31
#pragma unroll
  for (int r = 0; r < 16; ++r) {
    int crow = (r & 3) + ((r >> 2) << 3) + hi4;
    float lr = __shfl(rl, crow, 32);
    int orow = q0 + crow;
#pragma unroll
    for (int db = 0; db < 2; ++db) {
      int dcol = h * 64 + db * 32 + l31;
      O[(size_t)(b * SEQ + orow) * DIM + dcol] = f2bf(oacc[db][r] * lr);
    }
  }
}

extern "C" void kernel_launch(void* const* d_in, const int* in_sizes, int n_in,
                              void* d_out, int out_size, void* d_ws,
                              size_t ws_size, hipStream_t stream) {
  const float* x = (const float*)d_in[0];
  const float* fsin = (const float*)d_in[1];
  const float* fcos = (const float*)d_in[2];
  const float* wq = (const float*)d_in[3];
  const float* wk = (const float*)d_in[4];
  const float* wv = (const float*)d_in[5];
  const float* wo = (const float*)d_in[6];
  const float* q_scale = (const float*)d_in[7];
  const float* q_bias = (const float*)d_in[8];
  const float* k_scale = (const float*)d_in[9];
  const float* k_bias = (const float*)d_in[10];
  float* out = (float*)d_out;

  u16* xb = (u16*)d_ws;                       // 4096*1024 bf16
  u16* wqkvT = xb + (size_t)ROWS * DIM;       // 3072*1024
  u16* woT = wqkvT + (size_t)3 * DIM * DIM;   // 1024*1024
  u16* qkv = woT + (size_t)DIM * DIM;         // 4096*3072 bf16
  u16* Qb = qkv + (size_t)ROWS * 3 * DIM;     // 32*2048*64
  u16* Kb = Qb + (size_t)BATCH * NH * SEQ * HD;
  u16* Vt = Kb + (size_t)BATCH * NH * SEQ * HD;
  u16* attnb = Vt + (size_t)BATCH * NH * SEQ * HD;  // 4096*1024

  prep<<<8192, 256, 0, stream>>>(x, wq, wk, wv, wo, xb, wqkvT, woT);
  gemm_bt<true><<<(ROWS / 128) * (3 * DIM / 128), 256, 0, stream>>>(
      xb, wqkvT, (void*)qkv, ROWS, 3 * DIM, DIM);
  post_qk<<<ROWS, 256, 0, stream>>>(qkv, fsin, fcos, q_scale, q_bias, k_scale,
                                    k_bias, Qb, Kb);
  post_v<<<BATCH * NH * (SEQ / 64), 256, 0, stream>>>(qkv, Vt);
  attn_fwd<<<(BATCH * NH * SEQ) / 64, 128, 0, stream>>>(Qb, Kb, Vt, attnb);
  gemm_bt<false><<<(ROWS / 128) * (DIM / 128), 256, 0, stream>>>(
      attnb, woT, (void*)out, ROWS, DIM, DIM);
}